// Round 1
// 641.268 us; speedup vs baseline: 1.0030x; 1.0030x over previous
//
#include <hip/hip_runtime.h>
#include <math.h>

#define NB 32       // batch
#define NS 2048     // seq
#define NE 1024     // embed
#define NR 512      // reasoning dim
#define FR 2048     // 4*NR
#define NSTEPS 8
#define MID_BLOCKS 64

// workspace layout (float offsets)
#define SCAL   ((size_t)0)                       // scalars (memset to 0 each call)
//   [0] enc|W|sum [1] dec|W|sum [2] gate|W|sum
//   [4] mean absmax (uint bits) [5] final absmax (uint bits)
//   [8..15] per-step h absmax (uint bits)
//   [64..319] gate logits [8 steps][32 batch]
//   uint[1020..1021] grid barrier (count, generation)
#define PART   ((size_t)1024)                     // 32*32*1024 partial seq sums
#define WB_IH  (PART + (size_t)NB*32*NE)          // 2048*512 bf16 W_ih (orig layout)
#define WB_SUM (WB_IH + (size_t)FR*NR/2)          // 2048*512 bf16 W_ih+W_hh
#define MEANB  (WB_SUM + (size_t)FR*NR/2)         // 32*1024 fp32
#define HBUF   (MEANB + (size_t)NB*NE)            // 9*32*512 fp32 (h0=enc out)
#define HBUFB  (HBUF + (size_t)9*NB*NR)           // 9*32*512 bf16
#define CBUF   (HBUFB + (size_t)9*NB*NR/2)        // 32*512 fp32
#define FINALB (CBUF + (size_t)NB*NR)             // 32*512 fp32
#define ROUTB  (FINALB + (size_t)NB*NR)           // 32*1024 fp32
#define ENCWB  (ROUTB + (size_t)NB*NE)            // 512*1024 bf16 ternarized encW
#define DECWB  (ENCWB + (size_t)NR*NE/2)          // 1024*512 bf16 ternarized decW
#define LOGIT  (SCAL + 64)

typedef __attribute__((ext_vector_type(8))) short bf16x8;
typedef __attribute__((ext_vector_type(4))) float f32x4;

__device__ __forceinline__ float sigf(float x){ return 1.0f/(1.0f+expf(-x)); }
__device__ __forceinline__ float quant8(float x, float isc){
    return fminf(fmaxf(rintf(x/isc), -128.0f), 127.0f);
}
__device__ __forceinline__ float tern(float w, float thr){
    return (fabsf(w) > thr) ? (w > 0.0f ? 1.0f : -1.0f) : 0.0f;
}
__device__ __forceinline__ unsigned short f2b(float x){   // fp32 -> bf16 RNE
    unsigned u = __float_as_uint(x);
    return (unsigned short)((u + 0x7fffu + ((u >> 16) & 1u)) >> 16);
}

// device-scope grid barrier for MID_BLOCKS co-resident blocks.
// All RMW atomics at agent scope (forced to the cross-XCD coherence point);
// __threadfence() provides the wbL2/inv release/acquire around it.
__device__ __forceinline__ void gridbar(unsigned* bar) {
    __syncthreads();
    if (threadIdx.x == 0) {
        __threadfence();   // release: publish this block's prior writes
        unsigned g = __hip_atomic_fetch_add(bar+1, 0u, __ATOMIC_RELAXED, __HIP_MEMORY_SCOPE_AGENT);
        unsigned a = __hip_atomic_fetch_add(bar,   1u, __ATOMIC_ACQ_REL, __HIP_MEMORY_SCOPE_AGENT);
        if (a == (unsigned)(MID_BLOCKS - 1)) {
            (void)__hip_atomic_exchange(bar, 0u, __ATOMIC_RELAXED, __HIP_MEMORY_SCOPE_AGENT);
            (void)__hip_atomic_fetch_add(bar+1, 1u, __ATOMIC_ACQ_REL, __HIP_MEMORY_SCOPE_AGENT);
        } else {
            while (__hip_atomic_fetch_add(bar+1, 0u, __ATOMIC_RELAXED, __HIP_MEMORY_SCOPE_AGENT) == g)
                __builtin_amdgcn_s_sleep(4);
        }
        __threadfence();   // acquire: invalidate so subsequent reads are fresh
    }
    __syncthreads();
}

// ---------------- K_pre: x partial sums + bf16 weight converts + |W| sums ----------------
__global__ __launch_bounds__(256) void k_pre(
    const float4* __restrict__ x4, const float* __restrict__ Wih,
    const float* __restrict__ Whh, const float* __restrict__ encW,
    const float* __restrict__ decW, const float* __restrict__ gateW,
    float* __restrict__ ws)
{
    const int blk = blockIdx.x, tid = threadIdx.x;
    if (blk < 1024) {
        // partial sums over seq: block = (b, chunk of 64 rows)
        const int b = blk >> 5, ch = blk & 31;
        const float4* xp = x4 + ((size_t)(b*NS + ch*64))*(NE/4) + tid;
        float4 a; a.x=0.f; a.y=0.f; a.z=0.f; a.w=0.f;
        #pragma unroll 4
        for (int i = 0; i < 64; i++) {
            float4 v = xp[(size_t)i*(NE/4)];
            a.x += v.x; a.y += v.y; a.z += v.z; a.w += v.w;
        }
        float4* pp = (float4*)(ws + PART) + (size_t)blk*(NE/4) + tid;
        *pp = a;
    } else if (blk < 1152) {
        // bf16 convert: W_ih and (W_ih+W_hh), original [2048][512] layout
        const int lb = blk - 1024;
        const float4* wih4 = (const float4*)Wih;
        const float4* whh4 = (const float4*)Whh;
        ushort4* bi = (ushort4*)(ws + WB_IH);
        ushort4* bs = (ushort4*)(ws + WB_SUM);
        #pragma unroll
        for (int i = 0; i < 8; i++) {
            const int idx = lb*256 + tid + i*32768;   // 128*256=32768; 8 iters -> 262144 float4s
            float4 a = wih4[idx];
            float4 c = whh4[idx];
            ushort4 va; va.x=f2b(a.x); va.y=f2b(a.y); va.z=f2b(a.z); va.w=f2b(a.w);
            ushort4 vs; vs.x=f2b(a.x+c.x); vs.y=f2b(a.y+c.y); vs.z=f2b(a.z+c.z); vs.w=f2b(a.w+c.w);
            bi[idx] = va; bs[idx] = vs;
        }
    } else {
        // abs-sum reductions
        const float4* w4; int n4; int lb; float* dst;
        if (blk < 1216)      { w4=(const float4*)encW;  n4=NR*NE/4; lb=blk-1152; dst=ws+SCAL+0; }
        else if (blk < 1280) { w4=(const float4*)decW;  n4=NE*NR/4; lb=blk-1216; dst=ws+SCAL+1; }
        else                 { w4=(const float4*)gateW; n4=NR/4;    lb=0;        dst=ws+SCAL+2; }
        float a = 0.f;
        for (int i = lb*256 + tid; i < n4; i += 64*256) {
            float4 v = w4[i];
            a += fabsf(v.x)+fabsf(v.y)+fabsf(v.z)+fabsf(v.w);
        }
        for (int o = 32; o > 0; o >>= 1) a += __shfl_down(a, o, 64);
        __shared__ float lds[4];
        if ((tid & 63) == 0) lds[tid >> 6] = a;
        __syncthreads();
        if (tid == 0) atomicAdd(dst, lds[0]+lds[1]+lds[2]+lds[3]);
    }
}

// ---------------- K_mid: everything between k_pre and k_out, one persistent kernel ----------------
// 64 blocks x 256 threads, all co-resident; phases separated by gridbar().
__global__ __launch_bounds__(256, 1) void k_mid(
    const float* __restrict__ encW, const float* __restrict__ encB,
    const float* __restrict__ decW, const float* __restrict__ decB,
    const float* __restrict__ gateW, const float* __restrict__ gateB,
    const float* __restrict__ bih, const float* __restrict__ bhh,
    float* __restrict__ ws)
{
    const int bid = blockIdx.x, tid = threadIdx.x;
    const int wv = tid >> 6, lane = tid & 63;
    const int n = lane & 15, quad = lane >> 4;
    unsigned* bar = (unsigned*)ws + 1020;

    __shared__ float sG[4][16][17];
    __shared__ float sRed[4];
    __shared__ float sQgw[NR];
    __shared__ float sLp[256];
    __shared__ int sAllneg[NSTEPS];

    // ======== P0: mean+absmax (blocks 0-31) | ternarize enc/dec weights (blocks 32-63) ========
    if (bid < 32) {
        const float4* pp = (const float4*)(ws + PART) + (size_t)bid*32*(NE/4);
        float4 a; a.x=0.f; a.y=0.f; a.z=0.f; a.w=0.f;
        #pragma unroll 4
        for (int c = 0; c < 32; c++) {
            float4 v = pp[(size_t)c*(NE/4) + tid];
            a.x += v.x; a.y += v.y; a.z += v.z; a.w += v.w;
        }
        const float inv = 1.0f/(float)NS;
        a.x *= inv; a.y *= inv; a.z *= inv; a.w *= inv;
        ((float4*)(ws + MEANB))[(size_t)bid*(NE/4) + tid] = a;
        float m = fmaxf(fmaxf(fabsf(a.x), fabsf(a.y)), fmaxf(fabsf(a.z), fabsf(a.w)));
        for (int o = 32; o > 0; o >>= 1) m = fmaxf(m, __shfl_down(m, o, 64));
        if (lane == 0) sRed[wv] = m;
        __syncthreads();
        if (tid == 0) {
            m = fmaxf(fmaxf(sRed[0], sRed[1]), fmaxf(sRed[2], sRed[3]));
            atomicMax((unsigned int*)(ws + SCAL) + 4, __float_as_uint(m));
        }
    } else {
        const int lb = bid - 32;
        const float* W; const float* scal; ushort4* dst; int base;
        if (lb < 16) { W = encW; scal = ws+SCAL+0; dst = (ushort4*)(ws+ENCWB); base = lb; }
        else         { W = decW; scal = ws+SCAL+1; dst = (ushort4*)(ws+DECWB); base = lb-16; }
        const float wsc = *scal * (1.0f/(float)(NR*NE));
        const float thr = 0.5f*wsc;
        const float4* w4 = (const float4*)W;
        #pragma unroll 4
        for (int i = 0; i < 32; i++) {
            const int idx = base*8192 + i*256 + tid;
            float4 w = w4[idx];
            ushort4 v;
            v.x = f2b(tern(w.x, thr)); v.y = f2b(tern(w.y, thr));
            v.z = f2b(tern(w.z, thr)); v.w = f2b(tern(w.w, thr));
            dst[idx] = v;
        }
    }
    gridbar(bar);

    // ======== P1: enc = bit_linear(mean, enc_W) via MFMA; h0, c=0 ========
    // 64 blocks: mt=bid&1 (16 batches), r-tile = bid>>1 (16 r). 4 waves split K=1024.
    {
        const int mt = bid & 1, r0 = (bid >> 1) << 4;
        const float amax = __uint_as_float(((const unsigned int*)(ws + SCAL))[4]);
        const float isc = amax * (1.0f/127.0f);
        const float wsc = ws[SCAL+0] * (1.0f/(float)(NR*NE));
        const float* arow = ws + MEANB + (size_t)(mt*16 + n)*NE + wv*256 + quad*8;
        const unsigned short* bp = (const unsigned short*)(ws + ENCWB)
                                   + (size_t)(r0 + n)*NE + wv*256 + quad*8;
        f32x4 acc = {0.f, 0.f, 0.f, 0.f};
        #pragma unroll
        for (int k0 = 0; k0 < 256; k0 += 32) {
            float4 a0 = *(const float4*)(arow + k0);
            float4 a1 = *(const float4*)(arow + k0 + 4);
            bf16x8 af;
            af[0]=(short)f2b(quant8(a0.x,isc)); af[1]=(short)f2b(quant8(a0.y,isc));
            af[2]=(short)f2b(quant8(a0.z,isc)); af[3]=(short)f2b(quant8(a0.w,isc));
            af[4]=(short)f2b(quant8(a1.x,isc)); af[5]=(short)f2b(quant8(a1.y,isc));
            af[6]=(short)f2b(quant8(a1.z,isc)); af[7]=(short)f2b(quant8(a1.w,isc));
            bf16x8 bf_ = *(const bf16x8*)(bp + k0);
            acc = __builtin_amdgcn_mfma_f32_16x16x32_bf16(af, bf_, acc, 0, 0, 0);
        }
        #pragma unroll
        for (int reg = 0; reg < 4; reg++) sG[wv][quad*4 + reg][n] = acc[reg];
        __syncthreads();
        const int bl = tid >> 4, rl = tid & 15;
        const float v = sG[0][bl][rl] + sG[1][bl][rl] + sG[2][bl][rl] + sG[3][bl][rl];
        const int b = mt*16 + bl, r = r0 + rl;
        const float h0 = v*wsc*isc + encB[r];
        ws[HBUF + (size_t)b*NR + r] = h0;
        ((unsigned short*)(ws + HBUFB))[(size_t)b*NR + r] = f2b(h0);
        ws[CBUF + (size_t)b*NR + r] = 0.f;
    }
    gridbar(bar);

    // ======== P2..P9: 8 LSTM steps (former k_step, barrier instead of relaunch) ========
    #pragma unroll 1
    for (int t = 0; t < NSTEPS; t++) {
        const unsigned short* wb = (const unsigned short*)(ws + (t == 0 ? WB_IH : WB_SUM));
        const int mt = bid & 1, r0 = (bid >> 1) << 4;
        const unsigned short* hb = (const unsigned short*)(ws + HBUFB) + (size_t)t*NB*NR;
        const unsigned short* ap = hb + (size_t)(mt*16 + n)*NR + quad*8;
        const unsigned short* bp = wb + (size_t)((wv << 9) + r0 + n)*NR + quad*8;
        f32x4 acc = {0.f, 0.f, 0.f, 0.f};
        #pragma unroll
        for (int k0 = 0; k0 < NR; k0 += 32) {
            bf16x8 af = *(const bf16x8*)(ap + k0);
            bf16x8 bf_ = *(const bf16x8*)(bp + k0);
            acc = __builtin_amdgcn_mfma_f32_16x16x32_bf16(af, bf_, acc, 0, 0, 0);
        }
        __syncthreads();
        #pragma unroll
        for (int reg = 0; reg < 4; reg++) sG[wv][quad*4 + reg][n] = acc[reg];
        __syncthreads();
        const int bl = tid >> 4, rl = tid & 15;
        const int r = r0 + rl, b = mt*16 + bl;
        const float gi = sG[0][bl][rl] + bih[r]        + bhh[r];
        const float gf = sG[1][bl][rl] + bih[NR+r]     + bhh[NR+r];
        const float gg = sG[2][bl][rl] + bih[2*NR+r]   + bhh[2*NR+r];
        const float go = sG[3][bl][rl] + bih[3*NR+r]   + bhh[3*NR+r];
        const float c  = ws[CBUF + (size_t)b*NR + r];
        const float cn = sigf(gf)*c + sigf(gi)*tanhf(gg);
        const float hn = sigf(go)*tanhf(cn);
        ws[CBUF + (size_t)b*NR + r] = cn;
        ws[HBUF + (size_t)(t+1)*NB*NR + (size_t)b*NR + r] = hn;
        ((unsigned short*)(ws + HBUFB))[(size_t)(t+1)*NB*NR + (size_t)b*NR + r] = f2b(hn);
        float m = fabsf(hn);
        for (int o = 32; o > 0; o >>= 1) m = fmaxf(m, __shfl_down(m, o, 64));
        if (lane == 0) sRed[wv] = m;
        __syncthreads();
        if (tid == 0) {
            m = fmaxf(fmaxf(sRed[0], sRed[1]), fmaxf(sRed[2], sRed[3]));
            atomicMax((unsigned int*)(ws + SCAL) + (8 + t), __float_as_uint(m));
        }
        gridbar(bar);
    }

    // ======== P10: gate logits (blocks 0-7, one step each) ========
    if (bid < NSTEPS) {
        const int t = bid;
        const float gwsc = ws[SCAL+2] * (1.0f/(float)NR);
        const float gthr = 0.5f*gwsc;
        for (int i = tid; i < NR; i += 256) sQgw[i] = tern(gateW[i], gthr);
        __syncthreads();
        const float amax = __uint_as_float(((const unsigned int*)(ws + SCAL))[8 + t]);
        const float isc = amax * (1.0f/127.0f);
        const float* h = ws + HBUF + (size_t)(t+1)*NB*NR;
        const int b = tid >> 3, ch = tid & 7;
        const float* hbp = h + (size_t)b*NR + ch*64;
        float s = 0.f;
        for (int i = 0; i < 64; i++) s += quant8(hbp[i], isc) * sQgw[ch*64 + i];
        sLp[tid] = s;
        __syncthreads();
        if (tid < NB) {
            float z = 0.f;
            for (int c2 = 0; c2 < 8; c2++) z += sLp[tid*8 + c2];
            ws[LOGIT + t*32 + tid] = z*gwsc*isc + gateB[0];
        }
    }
    gridbar(bar);

    // ======== P11: step weights + masked mean + final absmax ========
    {
        if (tid < NSTEPS) {
            int an = 1;
            for (int b = 0; b < NB; b++)
                an &= (ws[LOGIT + tid*32 + b] < 0.0f) ? 1 : 0;   // sigmoid(z)<0.5 <=> z<0
            sAllneg[tid] = an;
        }
        __syncthreads();
        float wts[NSTEPS]; bool active = true; float wsum = 0.f;
        #pragma unroll
        for (int t = 0; t < NSTEPS; t++) {
            const bool trig = (sAllneg[t] != 0) && (t > 2);
            wts[t] = active ? 1.0f : 0.0f;
            wsum += wts[t];
            active = active && !trig;
        }
        const float inv = 1.0f/wsum;
        const int i = bid*256 + tid;          // covers 32*512 = 16384
        float f = 0.f;
        #pragma unroll
        for (int t = 0; t < NSTEPS; t++)
            f += wts[t]*ws[HBUF + (size_t)(t+1)*NB*NR + i];
        f *= inv;
        ws[FINALB + i] = f;
        float m = fabsf(f);
        for (int o = 32; o > 0; o >>= 1) m = fmaxf(m, __shfl_down(m, o, 64));
        if (lane == 0) sRed[wv] = m;
        __syncthreads();
        if (tid == 0) {
            m = fmaxf(fmaxf(sRed[0], sRed[1]), fmaxf(sRed[2], sRed[3]));
            atomicMax((unsigned int*)(ws + SCAL) + 5, __float_as_uint(m));
        }
    }
    gridbar(bar);

    // ======== P12: dec = bit_linear(final, dec_W) via MFMA -> ROUTB ========
    // 128 16x16 tiles (2 mt x 64 e-tiles) over 64 blocks x waves 0,1; K=512.
    {
        const int mt = bid & 1, gp = bid >> 1;
        if (wv < 2) {
            const int e0 = (gp*2 + wv) << 4;
            const float isc = __uint_as_float(((const unsigned int*)(ws + SCAL))[5]) * (1.0f/127.0f);
            const float wsc = ws[SCAL+1] * (1.0f/(float)(NE*NR));
            const float* arow = ws + FINALB + (size_t)(mt*16 + n)*NR + quad*8;
            const unsigned short* bp = (const unsigned short*)(ws + DECWB)
                                       + (size_t)(e0 + n)*NR + quad*8;
            f32x4 acc = {0.f, 0.f, 0.f, 0.f};
            #pragma unroll
            for (int k0 = 0; k0 < NR; k0 += 32) {
                float4 a0 = *(const float4*)(arow + k0);
                float4 a1 = *(const float4*)(arow + k0 + 4);
                bf16x8 af;
                af[0]=(short)f2b(quant8(a0.x,isc)); af[1]=(short)f2b(quant8(a0.y,isc));
                af[2]=(short)f2b(quant8(a0.z,isc)); af[3]=(short)f2b(quant8(a0.w,isc));
                af[4]=(short)f2b(quant8(a1.x,isc)); af[5]=(short)f2b(quant8(a1.y,isc));
                af[6]=(short)f2b(quant8(a1.z,isc)); af[7]=(short)f2b(quant8(a1.w,isc));
                bf16x8 bf_ = *(const bf16x8*)(bp + k0);
                acc = __builtin_amdgcn_mfma_f32_16x16x32_bf16(af, bf_, acc, 0, 0, 0);
            }
            #pragma unroll
            for (int reg = 0; reg < 4; reg++) {
                const int b = mt*16 + quad*4 + reg;
                ws[ROUTB + (size_t)b*NE + e0 + n] = acc[reg]*wsc*isc + decB[e0 + n];
            }
        }
    }
}

// ---------------- K_out: out = x + r_out broadcast over seq ----------------
__global__ __launch_bounds__(256) void k_out(
    const float4* __restrict__ x4, const float* __restrict__ ws,
    float4* __restrict__ out4)
{
    const float4* r4 = (const float4*)(ws + ROUTB);
    const size_t base = (size_t)blockIdx.x*1024 + threadIdx.x;
    #pragma unroll
    for (int i = 0; i < 4; i++) {
        size_t f = base + (size_t)i*256;
        int e4 = (int)(f & 255);
        int b  = (int)(f >> 19);            // S*E/4 = 2^19 per batch
        float4 xv = x4[f];
        float4 rv = r4[(size_t)b*256 + e4];
        float4 o; o.x = xv.x+rv.x; o.y = xv.y+rv.y; o.z = xv.z+rv.z; o.w = xv.w+rv.w;
        out4[f] = o;
    }
}

extern "C" void kernel_launch(void* const* d_in, const int* in_sizes, int n_in,
                              void* d_out, int out_size, void* d_ws, size_t ws_size,
                              hipStream_t stream)
{
    const float* x     = (const float*)d_in[0];
    const float* encW  = (const float*)d_in[1];
    const float* encB  = (const float*)d_in[2];
    const float* Wih   = (const float*)d_in[3];
    const float* Whh   = (const float*)d_in[4];
    const float* bih   = (const float*)d_in[5];
    const float* bhh   = (const float*)d_in[6];
    const float* decW  = (const float*)d_in[7];
    const float* decB  = (const float*)d_in[8];
    const float* gateW = (const float*)d_in[9];
    const float* gateB = (const float*)d_in[10];
    float* ws  = (float*)d_ws;
    float* out = (float*)d_out;

    hipMemsetAsync(d_ws, 0, 4096, stream);   // zero scalar block (atomics + grid barrier)

    hipLaunchKernelGGL(k_pre, dim3(1281), dim3(256), 0, stream,
                       (const float4*)x, Wih, Whh, encW, decW, gateW, ws);
    hipLaunchKernelGGL(k_mid, dim3(MID_BLOCKS), dim3(256), 0, stream,
                       encW, encB, decW, decB, gateW, gateB, bih, bhh, ws);
    hipLaunchKernelGGL(k_out, dim3(16384), dim3(256), 0, stream,
                       (const float4*)x, ws, (float4*)out);
}